// Round 2
// 118.003 us; speedup vs baseline: 1.0199x; 1.0199x over previous
//
#include <hip/hip_runtime.h>
#include <math.h>

// DSVF via exact time-domain IIR (== reference's FFT overlap-add: pole
// radius r <= 0.55 robustly; warm-up truncation 0.55^32 ~ 5e-9 relative,
// ~1e-7 absolute vs 1.6e-2 tolerance).
//
// R6 = R5 with the nontemporal-store compile fix (HIP float4 is a class
// type; __builtin_nontemporal_store needs a clang ext_vector_type).
//
// R5 theory: occupancy / phase-overlap. R4 was ~1.8x over its 21 us memory
// floor with near-ideal traffic and trivial VALU load -> the gap is
// pipeline bubbles: 34 KB LDS capped residency at 4 blocks/CU, so the CU's
// memory pipe idled during compute/barrier phases. Fix: halve the tile
// (OUT_BLK 32->16, LDS ~17 KB -> 8 blocks/CU, the wave cap), halve the
// warm-up (64->32, still 5e-9 relative), force VGPR<=64 via
// __launch_bounds__(256,8), and stream the stores non-temporally.

#define N_PER_ROW (128 * 2048)     // 262144 samples per row
#define BATCH 64
#define TPB 256
#define OUT_BLK 16                 // outputs per thread
#define WARM 32                    // warm-up samples per thread
#define TILE (TPB * OUT_BLK)       // 4096 outputs per block
#define TILES_PER_ROW (N_PER_ROW / TILE)   // 64
#define LDS_LOGICAL (TILE + WARM)  // 4128 floats
#define LDS_FLOATS (LDS_LOGICAL + (LDS_LOGICAL / 32) + 4)  // padded

typedef float vfloat4 __attribute__((ext_vector_type(4)));

__device__ __forceinline__ int padidx(int L) { return L + (L >> 5); }

__global__ __launch_bounds__(256, 8) void dsvf_iir_kernel(
    const float* __restrict__ x,
    const float* __restrict__ g_p, const float* __restrict__ R_p,
    const float* __restrict__ mhp_p, const float* __restrict__ mbp_p,
    const float* __restrict__ mlp_p,
    float* __restrict__ out)
{
    __shared__ float lds[LDS_FLOATS];

    const int b   = blockIdx.x;
    const int row = b >> 6;                  // / TILES_PER_ROW (=64)
    const int tl  = b & (TILES_PER_ROW - 1);
    const size_t base = (size_t)row * N_PER_ROW + (size_t)tl * TILE;
    const float* __restrict__ src = x + base;
    const int k = threadIdx.x;

    // --- cooperative staging: halo (32 floats) + tile (4096 floats) ---
    if (k < WARM / 4) {                       // threads 0..7 load halo
        float4 v;
        if (tl == 0) { v.x = v.y = v.z = v.w = 0.0f; }  // zero state: exact
        else         { v = *((const float4*)(src - WARM) + k); }
        float* p = &lds[padidx(4 * k)];
        p[0] = v.x; p[1] = v.y; p[2] = v.z; p[3] = v.w;
    }
    {
        const float4* sp = (const float4*)src;
        #pragma unroll
        for (int m = 0; m < TILE / 4 / TPB; ++m) {    // 4 float4 each
            const int i = k + m * TPB;
            float4 v = sp[i];
            float* p = &lds[padidx(WARM + 4 * i)];
            p[0] = v.x; p[1] = v.y; p[2] = v.z; p[3] = v.w;
        }
    }

    // --- biquad coefficients (identical math to reference, fp32) ---
    const float g = g_p[0], R = R_p[0];
    const float m_hp = mhp_p[0], m_bp = mbp_p[0], m_lp = mlp_p[0];
    const float sig = 1.0f / (1.0f + expf(-g));
    const float gt  = tanf(1.5707963267948966f * sig);   // tan(pi*sig/2)
    const float Rt  = log1pf(expf(R));                   // softplus
    const float g2  = gt * gt;
    const float b0 = g2 * m_lp + gt * m_bp + m_hp;
    const float b1 = 2.0f * g2 * m_lp - 2.0f * m_hp;
    const float b2 = g2 * m_lp - gt * m_bp + m_hp;
    const float a0 = g2 + 2.0f * Rt * gt + 1.0f;
    const float a1 = 2.0f * g2 - 2.0f;
    const float a2 = g2 - 2.0f * Rt * gt + 1.0f;
    const float inv_a0 = 1.0f / a0;
    const float B0 = b0 * inv_a0, B1 = b1 * inv_a0, B2 = b2 * inv_a0;
    const float A1 = a1 * inv_a0, A2 = a2 * inv_a0;

    __syncthreads();

    // --- per-thread IIR over LDS window [k*16, k*16 + 48) (halo coords) ---
    float s1 = 0.0f, s2 = 0.0f;
    const int L0 = k * OUT_BLK;

#define STEP_D(xx) { float y_ = fmaf(B0, (xx), s1);                 \
                     s1 = fmaf(-A1, y_, fmaf(B1, (xx), s2));        \
                     s2 = fmaf(-A2, y_, B2 * (xx)); }
#define STEP_S(xx, yy) { (yy) = fmaf(B0, (xx), s1);                 \
                     s1 = fmaf(-A1, (yy), fmaf(B1, (xx), s2));      \
                     s2 = fmaf(-A2, (yy), B2 * (xx)); }

    #pragma unroll
    for (int j = 0; j < WARM / 4; ++j) {      // 8 warm float4s
        const float* p = &lds[padidx(L0 + 4 * j)];
        STEP_D(p[0]); STEP_D(p[1]); STEP_D(p[2]); STEP_D(p[3]);
    }

    float o[OUT_BLK];                         // outputs stay in VGPRs
    #pragma unroll
    for (int j = 0; j < OUT_BLK / 4; ++j) {
        const float* p = &lds[padidx(L0 + WARM + 4 * j)];
        STEP_S(p[0], o[4*j+0]); STEP_S(p[1], o[4*j+1]);
        STEP_S(p[2], o[4*j+2]); STEP_S(p[3], o[4*j+3]);
    }
#undef STEP_D
#undef STEP_S

    __syncthreads();   // all input reads done; safe to overwrite LDS

    // --- transpose-by-LDS: scatter outputs (2-way bank alias, free) ---
    #pragma unroll
    for (int j = 0; j < OUT_BLK; ++j) {
        lds[padidx(L0 + j)] = o[j];
    }

    __syncthreads();

    // --- cooperative coalesced store: 4 float4 per thread, non-temporal ---
    {
        vfloat4* dp = (vfloat4*)(out + base);
        #pragma unroll
        for (int m = 0; m < TILE / 4 / TPB; ++m) {
            const int i = k + m * TPB;
            const float* p = &lds[padidx(4 * i)];
            vfloat4 v;
            v.x = p[0]; v.y = p[1]; v.z = p[2]; v.w = p[3];
            __builtin_nontemporal_store(v, &dp[i]);
        }
    }
}

extern "C" void kernel_launch(void* const* d_in, const int* in_sizes, int n_in,
                              void* d_out, int out_size, void* d_ws, size_t ws_size,
                              hipStream_t stream) {
    const float* x    = (const float*)d_in[0];
    const float* g    = (const float*)d_in[1];
    const float* R    = (const float*)d_in[2];
    const float* m_hp = (const float*)d_in[3];
    const float* m_bp = (const float*)d_in[4];
    const float* m_lp = (const float*)d_in[5];
    float* out = (float*)d_out;

    dim3 block(TPB);
    dim3 grid(BATCH * TILES_PER_ROW);         // 4096 blocks
    dsvf_iir_kernel<<<grid, block, 0, stream>>>(x, g, R, m_hp, m_bp, m_lp, out);
}

// Round 3
// 117.092 us; speedup vs baseline: 1.0278x; 1.0078x over previous
//
#include <hip/hip_runtime.h>
#include <math.h>

// DSVF via exact time-domain IIR (== reference's FFT overlap-add: pole
// radius r <= 0.55 robustly; warm-up truncation 0.55^32 ~ 5e-9 relative,
// ~1e-7 absolute vs 1.6e-2 tolerance).
//
// R7: ZERO-BARRIER wave-private tiles. R6 reached ~33 us (4.1 TB/s) vs the
// 21 us / 6.3 TB/s floor; fills on the same buffers hit 6.4 TB/s, so the
// gap is intra-kernel: block-wide __syncthreads ladder stalls all 4 waves
// of a block together at every phase edge, draining the memory pipe.
// Nothing needs block scope: each wave owns a 1024-output subtile + its
// own 32-sample halo in a wave-private LDS region. Within-wave
// producer->consumer ordering is free (lgkmcnt), so ALL barriers go away
// and 32 independent waves/CU free-run at arbitrary phase offsets.

#define N_PER_ROW (128 * 2048)     // 262144 samples per row
#define BATCH 64
#define TPB 256
#define OUT_BLK 16                 // outputs per thread
#define WARM 32                    // warm-up samples per thread
#define WTILE (64 * OUT_BLK)       // 1024 outputs per wave
#define TILE (TPB * OUT_BLK)       // 4096 outputs per block
#define TILES_PER_ROW (N_PER_ROW / TILE)   // 64
#define WREG 1092                  // padded wave region: padidx(1055)=1087 -> 1092

typedef float vfloat4 __attribute__((ext_vector_type(4)));

__device__ __forceinline__ int padidx(int L) { return L + (L >> 5); }

__global__ __launch_bounds__(256, 8) void dsvf_iir_kernel(
    const float* __restrict__ x,
    const float* __restrict__ g_p, const float* __restrict__ R_p,
    const float* __restrict__ mhp_p, const float* __restrict__ mbp_p,
    const float* __restrict__ mlp_p,
    float* __restrict__ out)
{
    __shared__ float lds[4 * WREG];          // 4 wave-private regions

    const int b    = blockIdx.x;
    const int row  = b >> 6;                 // / TILES_PER_ROW (=64)
    const int tl   = b & (TILES_PER_ROW - 1);
    const int k    = threadIdx.x;
    const int wid  = k >> 6;                 // wave 0..3
    const int lane = k & 63;

    const size_t wbase = (size_t)row * N_PER_ROW + (size_t)tl * TILE
                       + (size_t)wid * WTILE;
    const float* __restrict__ src = x + wbase;
    float* const wlds = &lds[wid * WREG];

    // --- wave-private staging: halo (32 floats) + subtile (1024 floats) ---
    if (lane < WARM / 4) {                   // lanes 0..7 load halo
        float4 v;
        if (tl == 0 && wid == 0) { v.x = v.y = v.z = v.w = 0.0f; } // row start
        else                     { v = *((const float4*)(src - WARM) + lane); }
        float* p = &wlds[padidx(4 * lane)];
        p[0] = v.x; p[1] = v.y; p[2] = v.z; p[3] = v.w;
    }
    {
        const float4* sp = (const float4*)src;
        #pragma unroll
        for (int m = 0; m < WTILE / 4 / 64; ++m) {   // 4 float4 each
            const int i = lane + m * 64;
            float4 v = sp[i];
            float* p = &wlds[padidx(WARM + 4 * i)];
            p[0] = v.x; p[1] = v.y; p[2] = v.z; p[3] = v.w;
        }
    }

    // --- biquad coefficients (identical math to reference, fp32) ---
    const float g = g_p[0], R = R_p[0];
    const float m_hp = mhp_p[0], m_bp = mbp_p[0], m_lp = mlp_p[0];
    const float sig = 1.0f / (1.0f + expf(-g));
    const float gt  = tanf(1.5707963267948966f * sig);   // tan(pi*sig/2)
    const float Rt  = log1pf(expf(R));                   // softplus
    const float g2  = gt * gt;
    const float b0 = g2 * m_lp + gt * m_bp + m_hp;
    const float b1 = 2.0f * g2 * m_lp - 2.0f * m_hp;
    const float b2 = g2 * m_lp - gt * m_bp + m_hp;
    const float a0 = g2 + 2.0f * Rt * gt + 1.0f;
    const float a1 = 2.0f * g2 - 2.0f;
    const float a2 = g2 - 2.0f * Rt * gt + 1.0f;
    const float inv_a0 = 1.0f / a0;
    const float B0 = b0 * inv_a0, B1 = b1 * inv_a0, B2 = b2 * inv_a0;
    const float A1 = a1 * inv_a0, A2 = a2 * inv_a0;

    // --- per-thread IIR over wave-local window [lane*16, lane*16+48) ---
    // (no barrier: producer and consumer are the same wave; compiler
    //  inserts the lgkmcnt waits)
    float s1 = 0.0f, s2 = 0.0f;
    const int L0 = lane * OUT_BLK;

#define STEP_D(xx) { float y_ = fmaf(B0, (xx), s1);                 \
                     s1 = fmaf(-A1, y_, fmaf(B1, (xx), s2));        \
                     s2 = fmaf(-A2, y_, B2 * (xx)); }
#define STEP_S(xx, yy) { (yy) = fmaf(B0, (xx), s1);                 \
                     s1 = fmaf(-A1, (yy), fmaf(B1, (xx), s2));      \
                     s2 = fmaf(-A2, (yy), B2 * (xx)); }

    #pragma unroll
    for (int j = 0; j < WARM / 4; ++j) {      // 8 warm float4s
        const float* p = &wlds[padidx(L0 + 4 * j)];
        STEP_D(p[0]); STEP_D(p[1]); STEP_D(p[2]); STEP_D(p[3]);
    }

    float o[OUT_BLK];                         // outputs stay in VGPRs
    #pragma unroll
    for (int j = 0; j < OUT_BLK / 4; ++j) {
        const float* p = &wlds[padidx(L0 + WARM + 4 * j)];
        STEP_S(p[0], o[4*j+0]); STEP_S(p[1], o[4*j+1]);
        STEP_S(p[2], o[4*j+2]); STEP_S(p[3], o[4*j+3]);
    }
#undef STEP_D
#undef STEP_S

    // --- wave-local transpose-by-LDS (reads above already consumed) ---
    #pragma unroll
    for (int j = 0; j < OUT_BLK; ++j) {
        wlds[padidx(L0 + j)] = o[j];
    }

    // --- coalesced nt store: 4 float4 per lane ---
    {
        vfloat4* dp = (vfloat4*)(out + wbase);
        #pragma unroll
        for (int m = 0; m < WTILE / 4 / 64; ++m) {
            const int i = lane + m * 64;
            const float* p = &wlds[padidx(4 * i)];
            vfloat4 v;
            v.x = p[0]; v.y = p[1]; v.z = p[2]; v.w = p[3];
            __builtin_nontemporal_store(v, &dp[i]);
        }
    }
}

extern "C" void kernel_launch(void* const* d_in, const int* in_sizes, int n_in,
                              void* d_out, int out_size, void* d_ws, size_t ws_size,
                              hipStream_t stream) {
    const float* x    = (const float*)d_in[0];
    const float* g    = (const float*)d_in[1];
    const float* R    = (const float*)d_in[2];
    const float* m_hp = (const float*)d_in[3];
    const float* m_bp = (const float*)d_in[4];
    const float* m_lp = (const float*)d_in[5];
    float* out = (float*)d_out;

    dim3 block(TPB);
    dim3 grid(BATCH * TILES_PER_ROW);         // 4096 blocks
    dsvf_iir_kernel<<<grid, block, 0, stream>>>(x, g, R, m_hp, m_bp, m_lp, out);
}